// Round 7
// baseline (200.560 us; speedup 1.0000x reference)
//
#include <hip/hip_runtime.h>
#include <hip/hip_bf16.h>
#include <math.h>

using bf16 = __hip_bfloat16;
typedef short short8 __attribute__((ext_vector_type(8)));   // 8 bf16 = 4 VGPRs
typedef float f32x4 __attribute__((ext_vector_type(4)));    // MFMA 16x16 acc

#define MFMA16 __builtin_amdgcn_mfma_f32_16x16x32_bf16
#define S_ 8192

// swizzled LDS addressing: tiles of 256B rows, 16 x 16B chunks, XOR swizzle.
__device__ __forceinline__ int sw(int r, int chunk) {
  return r * 256 + (((chunk) ^ (r & 15)) << 4);
}

__device__ __forceinline__ float gelu_exact(float y) {
  return 0.5f * y * (1.0f + erff(y * 0.70710678118654752f));
}

__device__ __forceinline__ unsigned pack2(float a, float b) {
  unsigned ra = (unsigned)__bfloat16_as_ushort(__float2bfloat16(a));
  unsigned rb = (unsigned)__bfloat16_as_ushort(__float2bfloat16(b));
  return ra | (rb << 16);
}

// ---- weight transpose+convert: Wt[m][n][k] = bf16(W[m][k][n]); 16 blocks ----
__global__ void transw(const float* __restrict__ wq, const float* __restrict__ wk,
                       const float* __restrict__ wv, const float* __restrict__ wo,
                       bf16* __restrict__ wt) {
  __shared__ bf16 s[32 * 136];
  int m = blockIdx.x >> 2, sl = blockIdx.x & 3;
  const float* W = (m == 0) ? wq : (m == 1) ? wk : (m == 2) ? wv : wo;
  for (int i = 0; i < 16; ++i) {
    int idx = threadIdx.x + i * 256;
    int k = idx >> 5, nl = idx & 31;
    s[nl * 136 + k] = __float2bfloat16(W[k * 128 + sl * 32 + nl]);
  }
  __syncthreads();
  for (int i = 0; i < 2; ++i) {
    int c = threadIdx.x + i * 256;
    int nl = c >> 4, ch = c & 15;
    *(uint4*)(wt + m * 16384 + (sl * 32 + nl) * 128 + ch * 8) =
        *(const uint4*)(s + nl * 136 + ch * 8);
  }
}

// ---- mm helpers ------------------------------------------------------------
__device__ __forceinline__ void clr8(f32x4 acc[8]) {
#pragma unroll
  for (int j = 0; j < 8; ++j) acc[j] = (f32x4){0.f, 0.f, 0.f, 0.f};
}

// A = strip in LDS (rows row0..row0+15, swizzled), B = global [n][k] bf16 rows
__device__ __forceinline__ void mm_g(const char* tA, const char* wB, int row0,
                                     int l15, int quad, f32x4 acc[8]) {
#pragma unroll
  for (int t = 0; t < 4; ++t) {
    short8 a = *(const short8*)(tA + sw(row0 + l15, 4 * t + quad));
#pragma unroll
    for (int ct = 0; ct < 8; ++ct) {
      short8 bb = *(const short8*)(wB + (ct * 16 + l15) * 256 + t * 64 + quad * 16);
      acc[ct] = MFMA16(a, bb, acc[ct], 0, 0, 0);
    }
  }
}

// A = strip in LDS, B = LDS tile stored [n][k] swizzled
__device__ __forceinline__ void mm_l(const char* tA, const char* tB, int row0,
                                     int l15, int quad, f32x4 acc[8]) {
#pragma unroll
  for (int t = 0; t < 4; ++t) {
    short8 a = *(const short8*)(tA + sw(row0 + l15, 4 * t + quad));
#pragma unroll
    for (int ct = 0; ct < 8; ++ct) {
      short8 bb = *(const short8*)(tB + sw(ct * 16 + l15, 4 * t + quad));
      acc[ct] = MFMA16(a, bb, acc[ct], 0, 0, 0);
    }
  }
}

// C/D strip -> row-major swizzled tile rows row0..row0+15, optional row scale
__device__ __forceinline__ void store_strip(char* tile, int row0, int l15, int quad,
                                            const f32x4 acc[8], const float* rs) {
#pragma unroll
  for (int ct = 0; ct < 8; ++ct) {
    int col = ct * 16 + l15;
#pragma unroll
    for (int r = 0; r < 4; ++r) {
      int row = row0 + quad * 4 + r;
      float v = acc[ct][r];
      if (rs) v *= rs[r];
      *(bf16*)(tile + sw(row, col >> 3) + (col & 7) * 2) = __float2bfloat16(v);
    }
  }
}

// stage 16x128 fp32 global rows -> bf16 swizzled wave-local strip (rows 0..15).
// Stores typed short8: TBAA-aliases the short8 MFMA A-reads (proven safe).
__device__ __forceinline__ void stage_x_strip(char* strip, const float* xg, int lane) {
#pragma unroll
  for (int i = 0; i < 4; ++i) {
    int e = lane * 32 + i * 8;
    float4 f0 = *(const float4*)(xg + e);
    float4 f1 = *(const float4*)(xg + e + 4);
    union { unsigned u[4]; short8 s; } pk;
    pk.u[0] = pack2(f0.x, f0.y); pk.u[1] = pack2(f0.z, f0.w);
    pk.u[2] = pack2(f1.x, f1.y); pk.u[3] = pack2(f1.z, f1.w);
    *(short8*)(strip + sw(e >> 7, (e >> 3) & 15)) = pk.s;
  }
}

// ---- stage 1: K rows + V^T blocks to global ---------------------------------
// 512 threads = 8 waves, one 128-row attention block per workgroup.
__global__ __launch_bounds__(512, 2) void proj_kv(
    const float* __restrict__ x, const bf16* __restrict__ wt,
    bf16* __restrict__ Kout, bf16* __restrict__ VTout) {
  __shared__ char lds[65536];               // 8 x 4KB X/K strips + 32KB VT tile
  char* vt = lds + 32768;
  const int tid = threadIdx.x;
  const int wave = tid >> 6, lane = tid & 63;
  const int l15 = lane & 15, quad = lane >> 4;
  char* strip = lds + wave * 4096;
  const size_t row0g = (size_t)blockIdx.x * 128 + wave * 16;  // global row
  stage_x_strip(strip, x + row0g * 128, lane);

  f32x4 aK[8], aV[8];
  clr8(aK);
  mm_g(strip, (const char*)(wt + 16384), 0, l15, quad, aK);
  clr8(aV);
  mm_g(strip, (const char*)(wt + 2 * 16384), 0, l15, quad, aV);

  // K strip over own (dead) X strip; wave-local short8 readback -> global rows
  store_strip(strip, 0, l15, quad, aK, nullptr);
#pragma unroll
  for (int i = 0; i < 4; ++i) {
    int unit = lane + i * 64;               // 16B units 0..255 of the 4KB strip
    int r = unit >> 4, ch = unit & 15;
    short8 v = *(const short8*)(strip + sw(r, ch));
    *(short8*)((short*)Kout + (row0g + r) * 128 + ch * 8) = v;
  }

  // V strip -> shared VT tile transposed: VT[d][u], u = wave*16 + quad*4 + r
  {
    int seq = wave * 16 + quad * 4;
#pragma unroll
    for (int ct = 0; ct < 8; ++ct) {
      int d = ct * 16 + l15;
      unsigned p[2] = {pack2(aV[ct][0], aV[ct][1]), pack2(aV[ct][2], aV[ct][3])};
      *(uint2*)(vt + sw(d, seq >> 3) + (seq & 7) * 2) = *(const uint2*)p;
    }
  }
  __syncthreads();                          // VT tile complete

  // coalesced VT readback -> global [block][d][u]
  bf16* vtg = VTout + (size_t)blockIdx.x * 16384;
#pragma unroll
  for (int i = 0; i < 4; ++i) {
    int idx = tid + i * 512;                // 16B units 0..2047
    short8 v = *(const short8*)(vt + sw(idx >> 4, idx & 15));
    *(short8*)((short*)vtg + idx * 8) = v;
  }
}

// ---- stage 2: fully wave-independent attention + LN + GELU ------------------
// 256 threads = 4 waves; each wave owns one 16-row strip; zero barriers.
__global__ __launch_bounds__(256, 4) void attn2(
    const float* __restrict__ x, const bf16* __restrict__ Kin,
    const bf16* __restrict__ VTin, const bf16* __restrict__ wt,
    const float* __restrict__ gamma, const float* __restrict__ beta,
    float* __restrict__ out) {
  __shared__ char lds[16384];               // 4 x 4KB wave strips
  const int tid = threadIdx.x;
  const int wave = tid >> 6, lane = tid & 63;
  const int l15 = lane & 15, quad = lane >> 4;
  char* strip = lds + wave * 4096;

  const int gsid = blockIdx.x * 4 + wave;   // global 16-row strip 0..4095
  const size_t r0 = (size_t)gsid * 16;      // first-half row
  const int b = (int)(r0 >> 13);            // batch
  const int rb = (int)(r0 & 8191);          // row within batch (first half)
  const int blkid = gsid >> 3;              // global 128-block 0..511
  float* outb = out + ((size_t)b * 16384 + rb) * 128;

  // second-half fill for this wave's 16 rows: gelu(beta) broadcast
  {
    float* o2 = out + ((size_t)b * 16384 + 8192 + rb) * 128;
    int c0 = (lane * 4) & 127;
    float4 bv = *(const float4*)(beta + c0);
    float4 gv;
    gv.x = gelu_exact(bv.x); gv.y = gelu_exact(bv.y);
    gv.z = gelu_exact(bv.z); gv.w = gelu_exact(bv.w);
#pragma unroll
    for (int j = 0; j < 8; ++j)
      *(float4*)(o2 + lane * 4 + j * 256) = gv;
  }

  stage_x_strip(strip, x + r0 * 128, lane);

  f32x4 acc[8];

  // Q = X @ Wq -> own strip
  clr8(acc);
  mm_g(strip, (const char*)(wt + 0), 0, l15, quad, acc);
  store_strip(strip, 0, l15, quad, acc, nullptr);

  // S = Q @ K^T  (B = K block rows, global/L2)
  clr8(acc);
  mm_g(strip, (const char*)(Kin + (size_t)blkid * 16384), 0, l15, quad, acc);

  // row softmax (no max subtraction; scores ~N(0,1) in fp32)
  float inv[4];
  const float sscale = 0.08838834764831845f;   // 1/sqrt(128)
#pragma unroll
  for (int r = 0; r < 4; ++r) {
    float sum = 0.f;
#pragma unroll
    for (int ct = 0; ct < 8; ++ct) {
      float v = __expf(acc[ct][r] * sscale);
      acc[ct][r] = v;
      sum += v;
    }
#pragma unroll
    for (int off = 8; off; off >>= 1) sum += __shfl_xor(sum, off, 64);
    inv[r] = 1.0f / sum;
  }
  store_strip(strip, 0, l15, quad, acc, nullptr);   // P over Q (own strip)

  // O = P @ V^T  (B = VT block rows, global/L2), fold 1/rowsum
  clr8(acc);
  mm_g(strip, (const char*)(VTin + (size_t)blkid * 16384), 0, l15, quad, acc);
  store_strip(strip, 0, l15, quad, acc, inv);       // O over P

  // H = O @ Wo
  clr8(acc);
  mm_g(strip, (const char*)(wt + 3 * 16384), 0, l15, quad, acc);

  // LayerNorm + exact GELU -> global fp32
  float gg[8], bbv[8];
#pragma unroll
  for (int ct = 0; ct < 8; ++ct) {
    gg[ct] = gamma[ct * 16 + l15];
    bbv[ct] = beta[ct * 16 + l15];
  }
#pragma unroll
  for (int r = 0; r < 4; ++r) {
    float sum = 0.f;
#pragma unroll
    for (int ct = 0; ct < 8; ++ct) sum += acc[ct][r];
#pragma unroll
    for (int off = 8; off; off >>= 1) sum += __shfl_xor(sum, off, 64);
    float mean = sum * (1.0f / 128.0f);
    float sq = 0.f;
#pragma unroll
    for (int ct = 0; ct < 8; ++ct) { float d = acc[ct][r] - mean; sq += d * d; }
#pragma unroll
    for (int off = 8; off; off >>= 1) sq += __shfl_xor(sq, off, 64);
    float rstd = rsqrtf(sq * (1.0f / 128.0f) + 1e-5f);
    int row = quad * 4 + r;
    float* op = outb + (size_t)row * 128;
#pragma unroll
    for (int ct = 0; ct < 8; ++ct) {
      float y = (acc[ct][r] - mean) * rstd * gg[ct] + bbv[ct];
      op[ct * 16 + l15] = gelu_exact(y);
    }
  }
}

// ---- fallback: round-4 fused kernel (used when ws too small for staging) ----
__global__ __launch_bounds__(512, 2) void attn_fb(
    const float* __restrict__ x, const bf16* __restrict__ wt,
    const float* __restrict__ gamma, const float* __restrict__ beta,
    float* __restrict__ out) {
  __shared__ uint4 ldsbuf[4096];
  char* t_x = (char*)ldsbuf;
  char* t_k = t_x + 32768;
  const int tid = threadIdx.x;
  const int wave = tid >> 6, lane = tid & 63;
  const int l15 = lane & 15, quad = lane >> 4;
  const int row0 = wave << 4;
  const int b = blockIdx.x >> 6, blk = blockIdx.x & 63;
  const float* xb = x + ((size_t)b * S_ + (size_t)blk * 128) * 128;
  float* outb = out + ((size_t)b * 2 * S_ + (size_t)blk * 128) * 128;
  {
    float* o2 = out + ((size_t)b * 2 * S_ + (size_t)(S_ + blk * 128)) * 128;
    int c0 = (tid * 4) & 127;
    float4 bv = *(const float4*)(beta + c0);
    float4 gv;
    gv.x = gelu_exact(bv.x); gv.y = gelu_exact(bv.y);
    gv.z = gelu_exact(bv.z); gv.w = gelu_exact(bv.w);
#pragma unroll
    for (int j = 0; j < 8; ++j) *(float4*)(o2 + tid * 4 + j * 2048) = gv;
  }
  stage_x_strip(t_x + wave * 4096, xb + (size_t)row0 * 128, lane);
  f32x4 acc[8];
  unsigned pV[16];
  clr8(acc);
  mm_g(t_x, (const char*)(wt + 16384), row0, l15, quad, acc);
  store_strip(t_k, row0, l15, quad, acc, nullptr);
  clr8(acc);
  mm_g(t_x, (const char*)(wt + 2 * 16384), row0, l15, quad, acc);
#pragma unroll
  for (int ct = 0; ct < 8; ++ct) {
    pV[2 * ct]     = pack2(acc[ct][0], acc[ct][1]);
    pV[2 * ct + 1] = pack2(acc[ct][2], acc[ct][3]);
  }
  clr8(acc);
  mm_g(t_x, (const char*)(wt + 0), row0, l15, quad, acc);
  store_strip(t_x, row0, l15, quad, acc, nullptr);
  __syncthreads();
  clr8(acc);
  mm_l(t_x, t_k, row0, l15, quad, acc);
  float inv[4];
  const float sscale = 0.08838834764831845f;
#pragma unroll
  for (int r = 0; r < 4; ++r) {
    float sum = 0.f;
#pragma unroll
    for (int ct = 0; ct < 8; ++ct) {
      float v = __expf(acc[ct][r] * sscale);
      acc[ct][r] = v; sum += v;
    }
#pragma unroll
    for (int off = 8; off; off >>= 1) sum += __shfl_xor(sum, off, 64);
    inv[r] = 1.0f / sum;
  }
  store_strip(t_x, row0, l15, quad, acc, nullptr);
  __syncthreads();
  {
    int seq = row0 + quad * 4;
#pragma unroll
    for (int ct = 0; ct < 8; ++ct) {
      int d = ct * 16 + l15;
      unsigned p[2] = {pV[2 * ct], pV[2 * ct + 1]};
      *(uint2*)(t_k + sw(d, seq >> 3) + (seq & 7) * 2) = *(const uint2*)p;
    }
  }
  __syncthreads();
  clr8(acc);
  mm_l(t_x, t_k, row0, l15, quad, acc);
  store_strip(t_x, row0, l15, quad, acc, inv);
  clr8(acc);
  mm_g(t_x, (const char*)(wt + 3 * 16384), row0, l15, quad, acc);
  float gg[8], bbv[8];
#pragma unroll
  for (int ct = 0; ct < 8; ++ct) { gg[ct] = gamma[ct * 16 + l15]; bbv[ct] = beta[ct * 16 + l15]; }
#pragma unroll
  for (int r = 0; r < 4; ++r) {
    float sum = 0.f;
#pragma unroll
    for (int ct = 0; ct < 8; ++ct) sum += acc[ct][r];
#pragma unroll
    for (int off = 8; off; off >>= 1) sum += __shfl_xor(sum, off, 64);
    float mean = sum * (1.0f / 128.0f);
    float sq = 0.f;
#pragma unroll
    for (int ct = 0; ct < 8; ++ct) { float d = acc[ct][r] - mean; sq += d * d; }
#pragma unroll
    for (int off = 8; off; off >>= 1) sq += __shfl_xor(sq, off, 64);
    float rstd = rsqrtf(sq * (1.0f / 128.0f) + 1e-5f);
    int row = row0 + quad * 4 + r;
    float* op = outb + (size_t)row * 128;
#pragma unroll
    for (int ct = 0; ct < 8; ++ct) {
      float y = (acc[ct][r] - mean) * rstd * gg[ct] + bbv[ct];
      op[ct * 16 + l15] = gelu_exact(y);
    }
  }
}

extern "C" void kernel_launch(void* const* d_in, const int* in_sizes, int n_in,
                              void* d_out, int out_size, void* d_ws, size_t ws_size,
                              hipStream_t stream) {
  const float* x     = (const float*)d_in[0];
  const float* wq    = (const float*)d_in[1];
  const float* wk    = (const float*)d_in[2];
  const float* wv    = (const float*)d_in[3];
  const float* wo    = (const float*)d_in[4];
  const float* gamma = (const float*)d_in[5];
  const float* beta  = (const float*)d_in[6];
  float* out = (float*)d_out;

  const size_t WT_BYTES = 4 * 16384 * sizeof(bf16);            // 128 KB
  const size_t KV_BYTES = (size_t)8 * S_ * 128 * sizeof(bf16); // 16 MB each
  bf16* wt = (bf16*)d_ws;

  transw<<<16, 256, 0, stream>>>(wq, wk, wv, wo, wt);

  if (ws_size >= WT_BYTES + 2 * KV_BYTES) {
    bf16* K  = (bf16*)((char*)d_ws + WT_BYTES);
    bf16* VT = (bf16*)((char*)d_ws + WT_BYTES + KV_BYTES);
    proj_kv<<<512, 512, 0, stream>>>(x, wt, K, VT);
    attn2<<<1024, 256, 0, stream>>>(x, K, VT, wt, gamma, beta, out);
  } else {
    attn_fb<<<512, 512, 0, stream>>>(x, wt, gamma, beta, out);
  }
}

// Round 8
// 172.993 us; speedup vs baseline: 1.1594x; 1.1594x over previous
//
#include <hip/hip_runtime.h>
#include <hip/hip_bf16.h>
#include <math.h>

using bf16 = __hip_bfloat16;
typedef short short8 __attribute__((ext_vector_type(8)));   // 8 bf16 = 4 VGPRs
typedef float f32x4 __attribute__((ext_vector_type(4)));    // MFMA 16x16 acc

#define MFMA16 __builtin_amdgcn_mfma_f32_16x16x32_bf16
#define S_ 8192

// swizzled LDS addressing: tiles of 256B rows, 16 x 16B chunks, XOR swizzle.
__device__ __forceinline__ int sw(int r, int chunk) {
  return r * 256 + (((chunk) ^ (r & 15)) << 4);
}

__device__ __forceinline__ float gelu_exact(float y) {
  return 0.5f * y * (1.0f + erff(y * 0.70710678118654752f));
}

__device__ __forceinline__ unsigned pack2(float a, float b) {
  unsigned ra = (unsigned)__bfloat16_as_ushort(__float2bfloat16(a));
  unsigned rb = (unsigned)__bfloat16_as_ushort(__float2bfloat16(b));
  return ra | (rb << 16);
}

// ---- weight transpose+convert: Wt[m][n][k] = bf16(W[m][k][n]); 16 blocks ----
__global__ void transw(const float* __restrict__ wq, const float* __restrict__ wk,
                       const float* __restrict__ wv, const float* __restrict__ wo,
                       bf16* __restrict__ wt) {
  __shared__ bf16 s[32 * 136];
  int m = blockIdx.x >> 2, sl = blockIdx.x & 3;
  const float* W = (m == 0) ? wq : (m == 1) ? wk : (m == 2) ? wv : wo;
  for (int i = 0; i < 16; ++i) {
    int idx = threadIdx.x + i * 256;
    int k = idx >> 5, nl = idx & 31;
    s[nl * 136 + k] = __float2bfloat16(W[k * 128 + sl * 32 + nl]);
  }
  __syncthreads();
  for (int i = 0; i < 2; ++i) {
    int c = threadIdx.x + i * 256;
    int nl = c >> 4, ch = c & 15;
    *(uint4*)(wt + m * 16384 + (sl * 32 + nl) * 128 + ch * 8) =
        *(const uint4*)(s + nl * 136 + ch * 8);
  }
}

// ---- mm helpers: burst-loaded operands for memory-level parallelism --------
__device__ __forceinline__ void clr8(f32x4 acc[8]) {
#pragma unroll
  for (int j = 0; j < 8; ++j) acc[j] = (f32x4){0.f, 0.f, 0.f, 0.f};
}

// A = strip in LDS (rows row0..row0+15, swizzled), B = global [n][k] bf16 rows.
// All 4 A-frags preloaded; 8 B-frags burst-loaded per t before any MFMA.
__device__ __forceinline__ void mm_g(const char* tA, const char* wB, int row0,
                                     int l15, int quad, f32x4 acc[8]) {
  short8 a[4];
#pragma unroll
  for (int t = 0; t < 4; ++t)
    a[t] = *(const short8*)(tA + sw(row0 + l15, 4 * t + quad));
#pragma unroll
  for (int t = 0; t < 4; ++t) {
    short8 b[8];
#pragma unroll
    for (int ct = 0; ct < 8; ++ct)
      b[ct] = *(const short8*)(wB + (ct * 16 + l15) * 256 + t * 64 + quad * 16);
#pragma unroll
    for (int ct = 0; ct < 8; ++ct)
      acc[ct] = MFMA16(a[t], b[ct], acc[ct], 0, 0, 0);
  }
}

// A = strip in LDS, B = LDS tile stored [n][k] swizzled; same burst shape.
__device__ __forceinline__ void mm_l(const char* tA, const char* tB, int row0,
                                     int l15, int quad, f32x4 acc[8]) {
  short8 a[4];
#pragma unroll
  for (int t = 0; t < 4; ++t)
    a[t] = *(const short8*)(tA + sw(row0 + l15, 4 * t + quad));
#pragma unroll
  for (int t = 0; t < 4; ++t) {
    short8 b[8];
#pragma unroll
    for (int ct = 0; ct < 8; ++ct)
      b[ct] = *(const short8*)(tB + sw(ct * 16 + l15, 4 * t + quad));
#pragma unroll
    for (int ct = 0; ct < 8; ++ct)
      acc[ct] = MFMA16(a[t], b[ct], acc[ct], 0, 0, 0);
  }
}

// C/D strip -> row-major swizzled tile rows row0..row0+15, optional row scale
__device__ __forceinline__ void store_strip(char* tile, int row0, int l15, int quad,
                                            const f32x4 acc[8], const float* rs) {
#pragma unroll
  for (int ct = 0; ct < 8; ++ct) {
    int col = ct * 16 + l15;
#pragma unroll
    for (int r = 0; r < 4; ++r) {
      int row = row0 + quad * 4 + r;
      float v = acc[ct][r];
      if (rs) v *= rs[r];
      *(bf16*)(tile + sw(row, col >> 3) + (col & 7) * 2) = __float2bfloat16(v);
    }
  }
}

// stage 16x128 fp32 global rows -> bf16 swizzled wave-local strip (rows 0..15).
// Stores typed short8: TBAA-aliases the short8 MFMA A-reads (proven safe).
__device__ __forceinline__ void stage_x_strip(char* strip, const float* xg, int lane) {
#pragma unroll
  for (int i = 0; i < 4; ++i) {
    int e = lane * 32 + i * 8;
    float4 f0 = *(const float4*)(xg + e);
    float4 f1 = *(const float4*)(xg + e + 4);
    union { unsigned u[4]; short8 s; } pk;
    pk.u[0] = pack2(f0.x, f0.y); pk.u[1] = pack2(f0.z, f0.w);
    pk.u[2] = pack2(f1.x, f1.y); pk.u[3] = pack2(f1.z, f1.w);
    *(short8*)(strip + sw(e >> 7, (e >> 3) & 15)) = pk.s;
  }
}

// ---- fused: QKV proj + attention + Wo + LN + GELU + second-half fill --------
// Round-4-proven structure; only the mm_* bodies changed (burst loads).
__global__ __launch_bounds__(512, 2) void attn_fused(
    const float* __restrict__ x, const bf16* __restrict__ wt,
    const float* __restrict__ gamma, const float* __restrict__ beta,
    float* __restrict__ out) {
  __shared__ uint4 ldsbuf[4096];            // 64 KB: 2 tiles
  char* t_x = (char*)ldsbuf;                // X -> Q -> P -> O (own strips)
  char* t_k = t_x + 32768;                  // K tile -> V^T tile

  const int tid = threadIdx.x;
  const int wave = tid >> 6, lane = tid & 63;
  const int l15 = lane & 15, quad = lane >> 4;
  const int row0 = wave << 4;               // own 16-row strip
  const int b = blockIdx.x >> 6, blk = blockIdx.x & 63;
  const float* xb = x + ((size_t)b * S_ + (size_t)blk * 128) * 128;
  float* outb = out + ((size_t)b * 2 * S_ + (size_t)blk * 128) * 128;

  // second-half fill: out2 = gelu(beta[d]) broadcast (stores drain under compute)
  {
    float* o2 = out + ((size_t)b * 2 * S_ + (size_t)(S_ + blk * 128)) * 128;
    int c0 = (tid * 4) & 127;
    float4 bv = *(const float4*)(beta + c0);
    float4 gv;
    gv.x = gelu_exact(bv.x); gv.y = gelu_exact(bv.y);
    gv.z = gelu_exact(bv.z); gv.w = gelu_exact(bv.w);
#pragma unroll
    for (int j = 0; j < 8; ++j)
      *(float4*)(o2 + tid * 4 + j * 2048) = gv;
  }

  // stage own X strip into the shared X tile (wave-local rows)
  stage_x_strip(t_x + wave * 4096, xb + (size_t)row0 * 128, lane);

  f32x4 acc[8];
  unsigned pV[16];                          // V strip packed bf16

  // K = X @ Wk -> t_k (own rows of shared K tile)
  clr8(acc);
  mm_g(t_x, (const char*)(wt + 16384), row0, l15, quad, acc);
  store_strip(t_k, row0, l15, quad, acc, nullptr);

  // V = X @ Wv -> packed registers
  clr8(acc);
  mm_g(t_x, (const char*)(wt + 2 * 16384), row0, l15, quad, acc);
#pragma unroll
  for (int ct = 0; ct < 8; ++ct) {
    pV[2 * ct]     = pack2(acc[ct][0], acc[ct][1]);
    pV[2 * ct + 1] = pack2(acc[ct][2], acc[ct][3]);
  }

  // Q = X @ Wq -> own strip (wave-local overwrite of own X rows)
  clr8(acc);
  mm_g(t_x, (const char*)(wt + 0), row0, l15, quad, acc);
  store_strip(t_x, row0, l15, quad, acc, nullptr);
  __syncthreads();                          // barrier 1: K tile fully visible

  // S = Q @ K^T
  clr8(acc);
  mm_l(t_x, t_k, row0, l15, quad, acc);

  // row softmax (no max subtraction; scores ~N(0,1) in fp32)
  float inv[4];
  const float sscale = 0.08838834764831845f;   // 1/sqrt(128)
#pragma unroll
  for (int r = 0; r < 4; ++r) {
    float sum = 0.f;
#pragma unroll
    for (int ct = 0; ct < 8; ++ct) {
      float v = __expf(acc[ct][r] * sscale);
      acc[ct][r] = v;
      sum += v;
    }
#pragma unroll
    for (int off = 8; off; off >>= 1) sum += __shfl_xor(sum, off, 64);
    inv[r] = 1.0f / sum;
  }
  store_strip(t_x, row0, l15, quad, acc, nullptr);  // P over Q (own strip)
  __syncthreads();                          // barrier 2: all done reading K

  // publish V^T over the K tile: VT[d][u], u = row0 + quad*4 + r
  {
    int seq = row0 + quad * 4;
#pragma unroll
    for (int ct = 0; ct < 8; ++ct) {
      int d = ct * 16 + l15;
      unsigned p[2] = {pV[2 * ct], pV[2 * ct + 1]};
      *(uint2*)(t_k + sw(d, seq >> 3) + (seq & 7) * 2) = *(const uint2*)p;
    }
  }
  __syncthreads();                          // barrier 3: V^T visible

  // O = P @ V^T (fold 1/rowsum)
  clr8(acc);
  mm_l(t_x, t_k, row0, l15, quad, acc);
  store_strip(t_x, row0, l15, quad, acc, inv);

  // H = O @ Wo
  clr8(acc);
  mm_g(t_x, (const char*)(wt + 3 * 16384), row0, l15, quad, acc);

  // LayerNorm + exact GELU -> global fp32
  float gg[8], bbv[8];
#pragma unroll
  for (int ct = 0; ct < 8; ++ct) {
    gg[ct] = gamma[ct * 16 + l15];
    bbv[ct] = beta[ct * 16 + l15];
  }
#pragma unroll
  for (int r = 0; r < 4; ++r) {
    float sum = 0.f;
#pragma unroll
    for (int ct = 0; ct < 8; ++ct) sum += acc[ct][r];
#pragma unroll
    for (int off = 8; off; off >>= 1) sum += __shfl_xor(sum, off, 64);
    float mean = sum * (1.0f / 128.0f);
    float sq = 0.f;
#pragma unroll
    for (int ct = 0; ct < 8; ++ct) { float d = acc[ct][r] - mean; sq += d * d; }
#pragma unroll
    for (int off = 8; off; off >>= 1) sq += __shfl_xor(sq, off, 64);
    float rstd = rsqrtf(sq * (1.0f / 128.0f) + 1e-5f);
    int row = row0 + quad * 4 + r;
    float* op = outb + (size_t)row * 128;
#pragma unroll
    for (int ct = 0; ct < 8; ++ct) {
      float y = (acc[ct][r] - mean) * rstd * gg[ct] + bbv[ct];
      op[ct * 16 + l15] = gelu_exact(y);
    }
  }
}

extern "C" void kernel_launch(void* const* d_in, const int* in_sizes, int n_in,
                              void* d_out, int out_size, void* d_ws, size_t ws_size,
                              hipStream_t stream) {
  const float* x     = (const float*)d_in[0];
  const float* wq    = (const float*)d_in[1];
  const float* wk    = (const float*)d_in[2];
  const float* wv    = (const float*)d_in[3];
  const float* wo    = (const float*)d_in[4];
  const float* gamma = (const float*)d_in[5];
  const float* beta  = (const float*)d_in[6];
  float* out = (float*)d_out;
  bf16* wt  = (bf16*)d_ws;                  // 4 x 128 x 128 bf16 = 128 KB

  transw<<<16, 256, 0, stream>>>(wq, wk, wv, wo, wt);
  attn_fused<<<512, 512, 0, stream>>>(x, wt, gamma, beta, out);
}

// Round 9
// 147.600 us; speedup vs baseline: 1.3588x; 1.1720x over previous
//
#include <hip/hip_runtime.h>
#include <hip/hip_bf16.h>
#include <math.h>

using bf16 = __hip_bfloat16;
typedef short short8 __attribute__((ext_vector_type(8)));   // 8 bf16 = 4 VGPRs
typedef short short4v __attribute__((ext_vector_type(4)));  // 4 bf16 = 2 VGPRs
typedef float f32x4 __attribute__((ext_vector_type(4)));    // MFMA 16x16 acc

#define MFMA16 __builtin_amdgcn_mfma_f32_16x16x32_bf16
#define S_ 8192

// swizzled LDS addressing: tiles of 256B rows, 16 x 16B chunks, XOR swizzle.
__device__ __forceinline__ int sw(int r, int chunk) {
  return r * 256 + (((chunk) ^ (r & 15)) << 4);
}

__device__ __forceinline__ float gelu_exact(float y) {
  return 0.5f * y * (1.0f + erff(y * 0.70710678118654752f));
}

__device__ __forceinline__ unsigned pack2(float a, float b) {
  unsigned ra = (unsigned)__bfloat16_as_ushort(__float2bfloat16(a));
  unsigned rb = (unsigned)__bfloat16_as_ushort(__float2bfloat16(b));
  return ra | (rb << 16);
}

// ---- weight convert to FRAGMENT-BLOCKED layout ------------------------------
// Fragment gf = ((ct*4 + t)*4 + quad)*16 + l15 holds B[k][n] with
// n = ct*16+l15, k = t*32 + quad*8 + j (j=0..7). mm_g reads frag gf at
// byte gf*16 -> 64 lanes consecutive 16B = 1KB contiguous per instruction.
__global__ void transw(const float* __restrict__ wq, const float* __restrict__ wk,
                       const float* __restrict__ wv, const float* __restrict__ wo,
                       bf16* __restrict__ wt) {
  __shared__ float smf[128 * 33];           // 128 k x 32 n slice, pad 33
  int m = blockIdx.x >> 2, sl = blockIdx.x & 3;
  const float* W = (m == 0) ? wq : (m == 1) ? wk : (m == 2) ? wv : wo;
  // load k=0..127, n = sl*32..sl*32+31
  for (int i = 0; i < 4; ++i) {
    int u = threadIdx.x + i * 256;          // 0..1023 float4 units
    int k = u >> 3, cg = u & 7;
    float4 v = *(const float4*)(W + k * 128 + sl * 32 + cg * 4);
    smf[k * 33 + cg * 4 + 0] = v.x;
    smf[k * 33 + cg * 4 + 1] = v.y;
    smf[k * 33 + cg * 4 + 2] = v.z;
    smf[k * 33 + cg * 4 + 3] = v.w;
  }
  __syncthreads();
  for (int i = 0; i < 2; ++i) {
    int f = threadIdx.x + i * 256;          // 0..511 local frags
    int l15 = f & 15, q = (f >> 4) & 3, t = (f >> 6) & 3, ctl = (f >> 8) & 1;
    int ct = sl * 2 + ctl;
    int gf = ((ct * 4 + t) * 4 + q) * 16 + l15;
    int k0 = t * 32 + q * 8, nl = ctl * 16 + l15;
    bf16 tmp[8];
#pragma unroll
    for (int j = 0; j < 8; ++j)
      tmp[j] = __float2bfloat16(smf[(k0 + j) * 33 + nl]);
    *(uint4*)(wt + m * 16384 + gf * 8) = *(const uint4*)tmp;
  }
}

// ---- mm helpers ------------------------------------------------------------
__device__ __forceinline__ void clr8(f32x4 acc[8]) {
#pragma unroll
  for (int j = 0; j < 8; ++j) acc[j] = (f32x4){0.f, 0.f, 0.f, 0.f};
}

// A = strip in LDS (rows row0..row0+15, swizzled), B = global fragment-blocked.
__device__ __forceinline__ void mm_g(const char* tA, const char* wB, int row0,
                                     int l15, int quad, f32x4 acc[8]) {
  short8 a[4];
#pragma unroll
  for (int t = 0; t < 4; ++t)
    a[t] = *(const short8*)(tA + sw(row0 + l15, 4 * t + quad));
#pragma unroll
  for (int t = 0; t < 4; ++t) {
    short8 b[8];
#pragma unroll
    for (int ct = 0; ct < 8; ++ct)
      b[ct] = *(const short8*)(wB + ((((ct * 4 + t) * 4 + quad) * 16 + l15) << 4));
#pragma unroll
    for (int ct = 0; ct < 8; ++ct)
      acc[ct] = MFMA16(a[t], b[ct], acc[ct], 0, 0, 0);
  }
}

// A = strip in LDS, B = LDS tile stored [n][k] swizzled
__device__ __forceinline__ void mm_l(const char* tA, const char* tB, int row0,
                                     int l15, int quad, f32x4 acc[8]) {
  short8 a[4];
#pragma unroll
  for (int t = 0; t < 4; ++t)
    a[t] = *(const short8*)(tA + sw(row0 + l15, 4 * t + quad));
#pragma unroll
  for (int t = 0; t < 4; ++t) {
    short8 b[8];
#pragma unroll
    for (int ct = 0; ct < 8; ++ct)
      b[ct] = *(const short8*)(tB + sw(ct * 16 + l15, 4 * t + quad));
#pragma unroll
    for (int ct = 0; ct < 8; ++ct)
      acc[ct] = MFMA16(a[t], b[ct], acc[ct], 0, 0, 0);
  }
}

// C/D strip -> row-major swizzled tile rows row0..row0+15, optional row scale
__device__ __forceinline__ void store_strip(char* tile, int row0, int l15, int quad,
                                            const f32x4 acc[8], const float* rs) {
#pragma unroll
  for (int ct = 0; ct < 8; ++ct) {
    int col = ct * 16 + l15;
#pragma unroll
    for (int r = 0; r < 4; ++r) {
      int row = row0 + quad * 4 + r;
      float v = acc[ct][r];
      if (rs) v *= rs[r];
      *(bf16*)(tile + sw(row, col >> 3) + (col & 7) * 2) = __float2bfloat16(v);
    }
  }
}

// stage 16x128 fp32 rows -> bf16 swizzled strip. COALESCED: lane*16B stride.
__device__ __forceinline__ void stage_x_strip(char* strip, const float* xg, int lane) {
#pragma unroll
  for (int it = 0; it < 8; ++it) {
    int e = it * 256 + lane * 4;            // element index
    float4 f = *(const float4*)(xg + e);
    union { unsigned u[2]; short4v s; } pk;
    pk.u[0] = pack2(f.x, f.y);
    pk.u[1] = pack2(f.z, f.w);
    int r = e >> 7, chunk = (e >> 3) & 15, half = (lane & 1) * 8;
    *(short4v*)(strip + sw(r, chunk) + half) = pk.s;
  }
  asm volatile("" ::: "memory");            // fence before short8 A-reads
}

// ---- fused: QKV proj + attention + Wo + LN + GELU + second-half fill --------
__global__ __launch_bounds__(512, 2) void attn_fused(
    const float* __restrict__ x, const bf16* __restrict__ wt,
    const float* __restrict__ gamma, const float* __restrict__ beta,
    float* __restrict__ out) {
  __shared__ uint4 ldsbuf[4096];            // 64 KB: 2 tiles
  char* t_x = (char*)ldsbuf;                // X -> Q -> P -> O (own strips)
  char* t_k = t_x + 32768;                  // K tile -> V^T tile

  const int tid = threadIdx.x;
  const int wave = tid >> 6, lane = tid & 63;
  const int l15 = lane & 15, quad = lane >> 4;
  const int row0 = wave << 4;               // own 16-row strip
  const int b = blockIdx.x >> 6, blk = blockIdx.x & 63;
  const float* xb = x + ((size_t)b * S_ + (size_t)blk * 128) * 128;
  float* outb = out + ((size_t)b * 2 * S_ + (size_t)blk * 128) * 128;

  // second-half fill: out2 = gelu(beta[d]) broadcast (coalesced float4 stores)
  {
    float* o2 = out + ((size_t)b * 2 * S_ + (size_t)(S_ + blk * 128)) * 128;
    int c0 = (tid * 4) & 127;
    float4 bv = *(const float4*)(beta + c0);
    float4 gv;
    gv.x = gelu_exact(bv.x); gv.y = gelu_exact(bv.y);
    gv.z = gelu_exact(bv.z); gv.w = gelu_exact(bv.w);
#pragma unroll
    for (int j = 0; j < 8; ++j)
      *(float4*)(o2 + tid * 4 + j * 2048) = gv;
  }

  // stage own X strip (coalesced global reads)
  stage_x_strip(t_x + wave * 4096, xb + (size_t)row0 * 128, lane);

  f32x4 acc[8];
  unsigned pV[16];                          // V strip packed bf16

  // K = X @ Wk -> t_k (own rows of shared K tile)
  clr8(acc);
  mm_g(t_x, (const char*)(wt + 16384), row0, l15, quad, acc);
  store_strip(t_k, row0, l15, quad, acc, nullptr);

  // V = X @ Wv -> packed registers
  clr8(acc);
  mm_g(t_x, (const char*)(wt + 2 * 16384), row0, l15, quad, acc);
#pragma unroll
  for (int ct = 0; ct < 8; ++ct) {
    pV[2 * ct]     = pack2(acc[ct][0], acc[ct][1]);
    pV[2 * ct + 1] = pack2(acc[ct][2], acc[ct][3]);
  }

  // Q = X @ Wq -> own strip (wave-local overwrite of own X rows)
  clr8(acc);
  mm_g(t_x, (const char*)(wt + 0), row0, l15, quad, acc);
  store_strip(t_x, row0, l15, quad, acc, nullptr);
  __syncthreads();                          // barrier 1: K tile fully visible

  // S = Q @ K^T
  clr8(acc);
  mm_l(t_x, t_k, row0, l15, quad, acc);

  // row softmax (no max subtraction; scores ~N(0,1) in fp32)
  float inv[4];
  const float sscale = 0.08838834764831845f;   // 1/sqrt(128)
#pragma unroll
  for (int r = 0; r < 4; ++r) {
    float sum = 0.f;
#pragma unroll
    for (int ct = 0; ct < 8; ++ct) {
      float v = __expf(acc[ct][r] * sscale);
      acc[ct][r] = v;
      sum += v;
    }
#pragma unroll
    for (int off = 8; off; off >>= 1) sum += __shfl_xor(sum, off, 64);
    inv[r] = 1.0f / sum;
  }
  store_strip(t_x, row0, l15, quad, acc, nullptr);  // P over Q (own strip)
  __syncthreads();                          // barrier 2: all done reading K

  // publish V^T over the K tile: VT[d][u], u = row0 + quad*4 + r
  {
    int seq = row0 + quad * 4;
#pragma unroll
    for (int ct = 0; ct < 8; ++ct) {
      int d = ct * 16 + l15;
      unsigned p[2] = {pV[2 * ct], pV[2 * ct + 1]};
      *(uint2*)(t_k + sw(d, seq >> 3) + (seq & 7) * 2) = *(const uint2*)p;
    }
  }
  __syncthreads();                          // barrier 3: V^T visible

  // O = P @ V^T (fold 1/rowsum)
  clr8(acc);
  mm_l(t_x, t_k, row0, l15, quad, acc);
  store_strip(t_x, row0, l15, quad, acc, inv);

  // H = O @ Wo
  clr8(acc);
  mm_g(t_x, (const char*)(wt + 3 * 16384), row0, l15, quad, acc);

  // LayerNorm stats per row
  float mean[4], rstd[4];
#pragma unroll
  for (int r = 0; r < 4; ++r) {
    float sum = 0.f;
#pragma unroll
    for (int ct = 0; ct < 8; ++ct) sum += acc[ct][r];
#pragma unroll
    for (int off = 8; off; off >>= 1) sum += __shfl_xor(sum, off, 64);
    mean[r] = sum * (1.0f / 128.0f);
    float sq = 0.f;
#pragma unroll
    for (int ct = 0; ct < 8; ++ct) { float d = acc[ct][r] - mean[r]; sq += d * d; }
#pragma unroll
    for (int off = 8; off; off >>= 1) sq += __shfl_xor(sq, off, 64);
    rstd[r] = rsqrtf(sq * (1.0f / 128.0f) + 1e-5f);
  }

  float gg[8], bbv[8];
#pragma unroll
  for (int ct = 0; ct < 8; ++ct) {
    gg[ct] = gamma[ct * 16 + l15];
    bbv[ct] = beta[ct * 16 + l15];
  }

  // GELU + coalesced store: stage 8 rows fp32 in own (dead) strip, read back
  // as float4, store 1KB contiguous bursts. 2 passes of 8 rows.
  float* fs = (float*)(t_x + wave * 4096);  // 8 x 128 fp32 = 4KB
#pragma unroll
  for (int p = 0; p < 2; ++p) {
    asm volatile("" ::: "memory");          // fence vs prior strip reads/pass
#pragma unroll
    for (int rr = 0; rr < 2; ++rr) {
      int r = 2 * p + rr;
      int s = quad * 2 + rr;
#pragma unroll
      for (int ct = 0; ct < 8; ++ct) {
        float y = (acc[ct][r] - mean[r]) * rstd[r] * gg[ct] + bbv[ct];
        fs[s * 128 + ct * 16 + l15] = gelu_exact(y);
      }
    }
    asm volatile("" ::: "memory");          // fence: f32 writes -> float4 reads
#pragma unroll
    for (int j = 0; j < 4; ++j) {
      int u = j * 64 + lane;                // 0..255 float4 units
      int s2 = u >> 5, coff = (u & 31) * 4;
      int grow = row0 + (s2 >> 1) * 4 + 2 * p + (s2 & 1);
      *(float4*)(outb + (size_t)grow * 128 + coff) = *(const float4*)(fs + s2 * 128 + coff);
    }
  }
}

extern "C" void kernel_launch(void* const* d_in, const int* in_sizes, int n_in,
                              void* d_out, int out_size, void* d_ws, size_t ws_size,
                              hipStream_t stream) {
  const float* x     = (const float*)d_in[0];
  const float* wq    = (const float*)d_in[1];
  const float* wk    = (const float*)d_in[2];
  const float* wv    = (const float*)d_in[3];
  const float* wo    = (const float*)d_in[4];
  const float* gamma = (const float*)d_in[5];
  const float* beta  = (const float*)d_in[6];
  float* out = (float*)d_out;
  bf16* wt  = (bf16*)d_ws;                  // 4 x 128 x 128 bf16 = 128 KB

  transw<<<16, 256, 0, stream>>>(wq, wk, wv, wo, wt);
  attn_fused<<<512, 512, 0, stream>>>(x, wt, gamma, beta, out);
}